// Round 13
// baseline (223.804 us; speedup 1.0000x reference)
//
#include <hip/hip_runtime.h>
#include <math.h>

// ---------------------------------------------------------------------------
// B=64 graphs, NN=133 nodes. R8-reanchor: EXACT round-8 kernel (verified:
// bench 188.6us, absmax 0.0; graph_k 78us + pack_k 79us). Rounds 9-11 all
// died to "container failed twice" across two structurally different
// variants -> diagnosed environmental; re-anchoring on known-good bytes
// rather than iterating blind. Known remaining headroom (next round if env
// recovers): pack_k's adj section is 64 blocks x 45 serial tiles (~75us of
// latency chains) -> parallelize to (graph,tile) blocks or self-pack.
// graph_k structure: all-MFMA dense path (adj packed to B-frag layout,
// orientation-matched producer/consumer LDS layouts, zero scalar LDS ops),
// pool/t4/tail on ballot pair lists in global ws.
// ---------------------------------------------------------------------------

#define NN 133
#define NPAIR 64
#define NW 16

#define A0 0
#define B0 37440
#define SH_HALFS 80448

typedef float v4f __attribute__((ext_vector_type(4)));
typedef _Float16 f16x8 __attribute__((ext_vector_type(8)));
typedef _Float16 f16x4 __attribute__((ext_vector_type(4)));
typedef _Float16 f16x2 __attribute__((ext_vector_type(2)));
typedef float f32x4 __attribute__((ext_vector_type(4)));

// packed-W segment offsets (halfs); tiles of 512 halfs = [64 lanes][8]
#define WP_EMB 0               // 10 mt * 3 ks
#define WP_GC1 15360           // 16 ct * 5 ks
#define WP_GC2 56320           // 8 ct * 8 ks
#define WP_GC3 89088           // 5 ct * 4 ks

struct Params {
    const float *x, *adj, *emb_w, *emb_b, *gc1_w, *gc1_b, *gc2_w, *gc2_b,
                *gc3_w, *gc3_b, *gc4_w, *gc4_b, *fc1_w, *fc1_b, *fin_w, *fin_b;
    const _Float16 *wp;
    const _Float16 *adjp;      // [64][45 tiles][64 lanes][8]
    float2 *gpairs;
    float *out;
};

// -------- prelude: weight pack (blocks 0..193) + adj pack (194..257) --------
__global__ __launch_bounds__(64)
void pack_k(const float* __restrict__ emb_w, const float* __restrict__ gc1_w,
            const float* __restrict__ gc2_w, const float* __restrict__ gc3_w,
            const float* __restrict__ adj,
            _Float16* __restrict__ wp, _Float16* __restrict__ adjp)
{
    const int t = blockIdx.x, lane = threadIdx.x;
    if (t < 194) {
        const float* W; int K, N, NKS, off, u;
        if (t < 30)       { W = emb_w; K = 75;  N = 150; NKS = 3; off = WP_EMB; u = t; }
        else if (t < 110) { W = gc1_w; K = 150; N = 256; NKS = 5; off = WP_GC1; u = t - 30; }
        else if (t < 174) { W = gc2_w; K = 256; N = 128; NKS = 8; off = WP_GC2; u = t - 110; }
        else              { W = gc3_w; K = 128; N = 75;  NKS = 4; off = WP_GC3; u = t - 174; }
        const int ct = u / NKS, ks = u % NKS;
        const int col = ct * 16 + (lane & 15);
        const int kb  = ks * 32 + (lane >> 4) * 8;
        f16x8 v;
#pragma unroll
        for (int j = 0; j < 8; ++j) {
            const int kk = kb + j;
            float w = W[(size_t)min(kk, K - 1) * N + min(col, N - 1)];
            if (kk >= K || col >= N) w = 0.f;
            v[j] = (_Float16)w;
        }
        *reinterpret_cast<f16x8*>(wp + (size_t)off + (size_t)u * 512 + lane * 8) = v;
    } else {
        const int g = t - 194;
        const float* ag = adj + (size_t)g * NN * NN;
        for (int u = 0; u < 45; ++u) {
            const int n  = (u / 5) * 16 + (lane & 15);
            const int kb = (u % 5) * 32 + (lane >> 4) * 8;
            f16x8 v;
#pragma unroll
            for (int j = 0; j < 8; ++j) {
                const int kk = kb + j;
                float w = (n < NN && kk < NN) ? ag[(size_t)n * NN + kk] : 0.f;
                v[j] = (_Float16)w;
            }
            *reinterpret_cast<f16x8*>(
                adjp + ((size_t)(g * 45 + u) * 64 + lane) * 8) = v;
        }
    }
}

// -------- ballot prep: pairs -> GLOBAL, counts -> LDS -----------------------
__device__ __forceinline__ void prep_row_g(
    const float* __restrict__ ar, float2* __restrict__ pb,
    int2* __restrict__ cS, int r, int lane)
{
    const unsigned long long lt = (1ull << lane) - 1ull;
    int base0 = 0, base1 = 0;
#pragma unroll
    for (int s = 0; s < 3; ++s) {
        const int j = lane + 64 * s;
        const float a = (j < NN) ? ar[j] : 0.f;
        const bool f = a > 1e-5f;
        const bool g = (a > 0.f) && !f;
        const unsigned long long mf = __ballot(f);
        const unsigned long long mg = __ballot(g);
        if (f) pb[base0 + __popcll(mf & lt)] =
                   make_float2(a, __int_as_float(j));
        if (g) pb[(NPAIR - 1) - (base1 + __popcll(mg & lt))] =
                   make_float2(a, __int_as_float(j));
        base0 += __popcll(mf);
        base1 += __popcll(mg);
    }
    if (lane == 0) cS[r] = make_int2(base0, base1);
}

// -------- swapped GEMM (emb): D=h0^T -> h0 row-major. A=wpack, B=x LDS ------
template<int MT, int NKS, int SSRC, int SDST, int N>
__device__ __forceinline__ void gemm_rm(
    const _Float16* __restrict__ wpA, const _Float16* __restrict__ src,
    const float* __restrict__ bias, _Float16* __restrict__ dst,
    int wave, int lane)
{
    const int lrow = lane & 15, lkb = lane >> 4;
    for (int t = wave; t < MT * 9; t += NW) {
        const int mt = t % MT, nt = t / MT;
        const _Float16* ap = wpA + (size_t)(mt * NKS) * 512 + lane * 8;
        const _Float16* bp = src + (nt * 16 + lrow) * SSRC + lkb * 8;
        f32x4 acc = {0.f, 0.f, 0.f, 0.f};
#pragma unroll
        for (int ks = 0; ks < NKS; ++ks) {
            f16x8 a = *reinterpret_cast<const f16x8*>(ap + ks * 512);
            f16x8 b = *reinterpret_cast<const f16x8*>(bp + ks * 32);
            acc = __builtin_amdgcn_mfma_f32_16x16x32_f16(a, b, acc, 0, 0, 0);
        }
        const int row = nt * 16 + lrow;
        const int c0  = mt * 16 + lkb * 4;
        f16x4 o;
#pragma unroll
        for (int i = 0; i < 4; ++i) {
            const int c = c0 + i;
            float v = 0.f;
            if (c < N) v = fmaxf(acc[i] + bias[c], 0.f);
            o[i] = (_Float16)v;
        }
        *reinterpret_cast<f16x4*>(dst + row * SDST + c0) = o;
    }
}

// -------- normal GEMM: t = p@W -> t col-major (b64). A=p LDS, B=wpack -------
template<int CT, int NKS, int SSRC>
__device__ __forceinline__ void gemm_cm(
    const _Float16* __restrict__ src, const _Float16* __restrict__ wpB,
    _Float16* __restrict__ t_cm, int wave, int lane)
{
    const int lrow = lane & 15, lkb = lane >> 4;
    for (int t = wave; t < CT * 9; t += NW) {
        const int ct = t % CT, rt = t / CT;
        const _Float16* ap = src + (rt * 16 + lrow) * SSRC + lkb * 8;
        const _Float16* bp = wpB + (size_t)(ct * NKS) * 512 + lane * 8;
        f32x4 acc = {0.f, 0.f, 0.f, 0.f};
#pragma unroll
        for (int ks = 0; ks < NKS; ++ks) {
            f16x8 a = *reinterpret_cast<const f16x8*>(ap + ks * 32);
            f16x8 b = *reinterpret_cast<const f16x8*>(bp + ks * 512);
            acc = __builtin_amdgcn_mfma_f32_16x16x32_f16(a, b, acc, 0, 0, 0);
        }
        const int col = ct * 16 + lrow;
        const int r0  = rt * 16 + lkb * 4;
        f16x4 o;
#pragma unroll
        for (int i = 0; i < 4; ++i) o[i] = (_Float16)acc[i];
        *reinterpret_cast<f16x4*>(t_cm + col * 168 + r0) = o;
    }
}

// -------- spmm: y^T = t^T (LDS) * adj^T (adjP) -> y row-major (b64) ---------
template<int MT, int SDST, int N>
__device__ __forceinline__ void spmm_mfma(
    const _Float16* __restrict__ t_cm, const _Float16* __restrict__ adjB,
    const float* __restrict__ bias, _Float16* __restrict__ y,
    int wave, int lane)
{
    const int lrow = lane & 15, lkb = lane >> 4;
    for (int t = wave; t < MT * 9; t += NW) {
        const int mt = t % MT, nt = t / MT;
        const _Float16* ap = t_cm + (mt * 16 + lrow) * 168 + lkb * 8;
        const _Float16* bp = adjB + (size_t)(nt * 5) * 512 + lane * 8;
        f32x4 acc = {0.f, 0.f, 0.f, 0.f};
#pragma unroll
        for (int ks = 0; ks < 5; ++ks) {
            f16x8 a = *reinterpret_cast<const f16x8*>(ap + ks * 32);
            f16x8 b = *reinterpret_cast<const f16x8*>(bp + ks * 512);
            acc = __builtin_amdgcn_mfma_f32_16x16x32_f16(a, b, acc, 0, 0, 0);
        }
        const int row = nt * 16 + lrow;
        const int c0  = mt * 16 + lkb * 4;
        f16x4 o;
#pragma unroll
        for (int i = 0; i < 4; ++i) {
            const int c = c0 + i;
            float v = 0.f;
            if (c < N) v = fmaxf(acc[i] + bias[c], 0.f);
            o[i] = (_Float16)v;
        }
        *reinterpret_cast<f16x4*>(y + row * SDST + c0) = o;
    }
}

// -------- pool, 4 cols/lane (N=256): y1(260) -> p1(264) ---------------------
__device__ __forceinline__ void pool4(
    const _Float16* __restrict__ yb,
    const float2* __restrict__ pb, int cx,
    _Float16* __restrict__ prow, int lane)
{
    const int c0 = 4 * lane;
    const float4* pq = reinterpret_cast<const float4*>(pb);
    float m0[4] = {}, m1[4] = {}, m2[4] = {}, m3[4] = {};
    int q = 0;
    for (; q + 4 <= cx; q += 4) {
        float4 p0 = pq[q >> 1], p1 = pq[(q >> 1) + 1];
        f16x4 r0 = *(const f16x4*)(yb + __float_as_int(p0.y) * 260 + c0);
        f16x4 r1 = *(const f16x4*)(yb + __float_as_int(p0.w) * 260 + c0);
        f16x4 r2 = *(const f16x4*)(yb + __float_as_int(p1.y) * 260 + c0);
        f16x4 r3 = *(const f16x4*)(yb + __float_as_int(p1.w) * 260 + c0);
#pragma unroll
        for (int u = 0; u < 4; ++u) {
            m0[u] = fmaxf(m0[u], (float)r0[u]);
            m1[u] = fmaxf(m1[u], (float)r1[u]);
            m2[u] = fmaxf(m2[u], (float)r2[u]);
            m3[u] = fmaxf(m3[u], (float)r3[u]);
        }
    }
    for (; q < cx; ++q) {
        f16x4 r = *(const f16x4*)(yb + __float_as_int(pb[q].y) * 260 + c0);
#pragma unroll
        for (int u = 0; u < 4; ++u) m0[u] = fmaxf(m0[u], (float)r[u]);
    }
    f16x4 o;
#pragma unroll
    for (int u = 0; u < 4; ++u)
        o[u] = (_Float16)fmaxf(fmaxf(m0[u], m1[u]), fmaxf(m2[u], m3[u]));
    *(f16x4*)(prow + c0) = o;
}

// -------- pool, 2 cols/lane (N=128): y2(136) -> p2(136) ---------------------
__device__ __forceinline__ void pool2(
    const _Float16* __restrict__ yb,
    const float2* __restrict__ pb, int cx,
    _Float16* __restrict__ prow, int lane)
{
    const int c0 = 2 * lane;
    if (c0 >= 128) return;
    const float4* pq = reinterpret_cast<const float4*>(pb);
    float m0[2] = {}, m1[2] = {}, m2[2] = {}, m3[2] = {};
    int q = 0;
    for (; q + 4 <= cx; q += 4) {
        float4 p0 = pq[q >> 1], p1 = pq[(q >> 1) + 1];
        f16x2 r0 = *(const f16x2*)(yb + __float_as_int(p0.y) * 136 + c0);
        f16x2 r1 = *(const f16x2*)(yb + __float_as_int(p0.w) * 136 + c0);
        f16x2 r2 = *(const f16x2*)(yb + __float_as_int(p1.y) * 136 + c0);
        f16x2 r3 = *(const f16x2*)(yb + __float_as_int(p1.w) * 136 + c0);
#pragma unroll
        for (int u = 0; u < 2; ++u) {
            m0[u] = fmaxf(m0[u], (float)r0[u]);
            m1[u] = fmaxf(m1[u], (float)r1[u]);
            m2[u] = fmaxf(m2[u], (float)r2[u]);
            m3[u] = fmaxf(m3[u], (float)r3[u]);
        }
    }
    for (; q < cx; ++q) {
        f16x2 r = *(const f16x2*)(yb + __float_as_int(pb[q].y) * 136 + c0);
#pragma unroll
        for (int u = 0; u < 2; ++u) m0[u] = fmaxf(m0[u], (float)r[u]);
    }
    f16x2 o;
#pragma unroll
    for (int u = 0; u < 2; ++u)
        o[u] = (_Float16)fmaxf(fmaxf(m0[u], m1[u]), fmaxf(m2[u], m3[u]));
    *(f16x2*)(prow + c0) = o;
}

// -------- t4: 2 cols/lane b32 reads from y3(80) -----------------------------
__device__ __forceinline__ void t4_row(
    const _Float16* __restrict__ yb,
    const float2* __restrict__ pb, int cx,
    const float* __restrict__ gc4_w,
    float* __restrict__ t4S, int r, int lane)
{
    const int c0 = 2 * lane;
    const int sc = min(c0, 78);
    const float gw0 = (c0 < 75) ? gc4_w[c0] : 0.f;
    const float gw1 = (c0 + 1 < 75) ? gc4_w[c0 + 1] : 0.f;
    const float4* pq = reinterpret_cast<const float4*>(pb);
    float m0a = 0.f, m1a = 0.f, m0b = 0.f, m1b = 0.f;
    float m0c = 0.f, m1c = 0.f, m0d = 0.f, m1d = 0.f;
    int q = 0;
    for (; q + 4 <= cx; q += 4) {
        float4 pA = pq[q >> 1], pB = pq[(q >> 1) + 1];
        f16x2 r0 = *(const f16x2*)(yb + __float_as_int(pA.y) * 80 + sc);
        f16x2 r1 = *(const f16x2*)(yb + __float_as_int(pA.w) * 80 + sc);
        f16x2 r2 = *(const f16x2*)(yb + __float_as_int(pB.y) * 80 + sc);
        f16x2 r3 = *(const f16x2*)(yb + __float_as_int(pB.w) * 80 + sc);
        m0a = fmaxf(m0a, (float)r0[0]); m1a = fmaxf(m1a, (float)r0[1]);
        m0b = fmaxf(m0b, (float)r1[0]); m1b = fmaxf(m1b, (float)r1[1]);
        m0c = fmaxf(m0c, (float)r2[0]); m1c = fmaxf(m1c, (float)r2[1]);
        m0d = fmaxf(m0d, (float)r3[0]); m1d = fmaxf(m1d, (float)r3[1]);
    }
    for (; q < cx; ++q) {
        f16x2 r = *(const f16x2*)(yb + __float_as_int(pb[q].y) * 80 + sc);
        m0a = fmaxf(m0a, (float)r[0]); m1a = fmaxf(m1a, (float)r[1]);
    }
    float m0 = fmaxf(fmaxf(m0a, m0b), fmaxf(m0c, m0d));
    float m1 = fmaxf(fmaxf(m1a, m1b), fmaxf(m1c, m1d));
    float v = m0 * gw0 + m1 * gw1;
#pragma unroll
    for (int off = 32; off; off >>= 1) v += __shfl_xor(v, off, 64);
    if (lane == 0) t4S[r] = v;
}

// --------------------------- one block = one graph --------------------------
__global__ __launch_bounds__(1024, 1)
void graph_k(Params P)
{
    __shared__ __align__(16) _Float16 SH[SH_HALFS];      // 160,896 B
    __shared__ int2  cS[NN];
    __shared__ float t4S[NN];
    __shared__ float y4S[NN];
    __shared__ float rS[3];

    const int b    = blockIdx.x;
    const int tid  = threadIdx.x;
    const int wave = tid >> 6, lane = tid & 63;

    float2* gp = P.gpairs + (size_t)b * NN * NPAIR;
    const _Float16* adjB = P.adjp + (size_t)b * 45 * 512;

    // S0: zero ALL scratch (finite => packed-operand zeros kill pads) + prep
    {
        v4f* z = reinterpret_cast<v4f*>(&SH[0]);
        for (int i = tid; i < SH_HALFS / 8; i += 1024)
            z[i] = v4f{0.f, 0.f, 0.f, 0.f};
    }
    for (int r = wave; r < NN; r += NW)
        prep_row_g(P.adj + ((size_t)b * NN + r) * NN, gp + (size_t)r * NPAIR,
                   cS, r, lane);
    __syncthreads();
    // S0a: x -> B0 row-major f16 (stride 104)
    for (int i = tid; i < NN * 75; i += 1024) {
        int r = i / 75, c = i - r * 75;
        SH[B0 + r * 104 + c] = (_Float16)P.x[(size_t)b * NN * 75 + i];
    }
    __syncthreads();
    // S1: emb (swapped): h0 = relu(x@emb_w+b) -> A0 row-major (stride 168)
    gemm_rm<10, 3, 104, 168, 150>(P.wp + WP_EMB, SH + B0, P.emb_b,
                                  SH + A0, wave, lane);
    __syncthreads();
    // S2: gemm1: t1 = h0 @ gc1_w -> B0 col-major (256 cols x 168)
    gemm_cm<16, 5, 168>(SH + A0, P.wp + WP_GC1, SH + B0, wave, lane);
    __syncthreads();
    // S3: spmm1: y1 = relu(adj@t1+b1) -> A0 row-major (stride 260)
    spmm_mfma<16, 260, 256>(SH + B0, adjB, P.gc1_b, SH + A0, wave, lane);
    __syncthreads();
    // S4: pool1: p1 -> B0 row-major (stride 264)
    for (int r = wave; r < NN; r += NW)
        pool4(SH + A0, gp + (size_t)r * NPAIR, cS[r].x,
              SH + B0 + r * 264, lane);
    __syncthreads();
    // S5: gemm2: t2 = p1 @ gc2_w -> A0 col-major (128 cols x 168)
    gemm_cm<8, 8, 264>(SH + B0, P.wp + WP_GC2, SH + A0, wave, lane);
    __syncthreads();
    // S6: spmm2: y2 -> B0 row-major (stride 136)
    spmm_mfma<8, 136, 128>(SH + A0, adjB, P.gc2_b, SH + B0, wave, lane);
    __syncthreads();
    // S7: pool2: p2 -> A0 row-major (stride 136)
    for (int r = wave; r < NN; r += NW)
        pool2(SH + B0, gp + (size_t)r * NPAIR, cS[r].x,
              SH + A0 + r * 136, lane);
    __syncthreads();
    // S8: gemm3: t3 = p2 @ gc3_w -> B0 col-major (80 cols x 168)
    gemm_cm<5, 4, 136>(SH + A0, P.wp + WP_GC3, SH + B0, wave, lane);
    __syncthreads();
    // S9: spmm3: y3 -> A0 row-major (stride 80, N=75)
    spmm_mfma<5, 80, 75>(SH + B0, adjB, P.gc3_b, SH + A0, wave, lane);
    __syncthreads();
    // S10: t4S[r] = pool3(y3)[r] . gc4_w
    for (int r = wave; r < NN; r += NW)
        t4_row(SH + A0, gp + (size_t)r * NPAIR, cS[r].x, P.gc4_w,
               t4S, r, lane);
    __syncthreads();
    // S11: tail — y4 = relu(A@t4+b4); fc1; fin; sigmoid
    if (tid < NN) {
        const float2* pb = gp + (size_t)tid * NPAIR;
        int2 c = cS[tid];
        float s = P.gc4_b[0];
        for (int q = 0; q < c.x; ++q) {
            float2 f = pb[q];
            s = fmaf(f.x, t4S[__float_as_int(f.y)], s);
        }
        for (int q = 0; q < c.y; ++q) {
            float2 f = pb[(NPAIR - 1) - q];
            s = fmaf(f.x, t4S[__float_as_int(f.y)], s);
        }
        y4S[tid] = fmaxf(s, 0.f);
    }
    __syncthreads();
    if (tid < 3) {
        float s = P.fc1_b[tid];
        for (int j = 0; j < 132; ++j)
            s = fmaf(y4S[1 + j], P.fc1_w[j * 3 + tid], s);
        rS[tid] = s;
    }
    __syncthreads();
    if (tid == 0) {
        float z = P.fin_b[0] + y4S[0] * P.fin_w[0] + rS[0] * P.fin_w[1]
                + rS[1] * P.fin_w[2] + rS[2] * P.fin_w[3];
        P.out[b] = 1.f / (1.f + expf(-z));
    }
}

extern "C" void kernel_launch(void* const* d_in, const int* in_sizes, int n_in,
                              void* d_out, int out_size, void* d_ws, size_t ws_size,
                              hipStream_t stream)
{
    // ws: wpack 199KB (->256KB) | adjP 2.95MB (->3MB) | gpairs 4.36MB
    _Float16* wp    = (_Float16*)d_ws;
    _Float16* adjp  = (_Float16*)((char*)d_ws + (256 << 10));
    float2*   gpairs = (float2*)((char*)d_ws + (256 << 10) + (3 << 20));

    Params hp;
    hp.x     = (const float*)d_in[0];
    hp.adj   = (const float*)d_in[1];
    hp.emb_w = (const float*)d_in[2];
    hp.emb_b = (const float*)d_in[3];
    hp.gc1_w = (const float*)d_in[4];
    hp.gc1_b = (const float*)d_in[5];
    hp.gc2_w = (const float*)d_in[6];
    hp.gc2_b = (const float*)d_in[7];
    hp.gc3_w = (const float*)d_in[8];
    hp.gc3_b = (const float*)d_in[9];
    hp.gc4_w = (const float*)d_in[10];
    hp.gc4_b = (const float*)d_in[11];
    hp.fc1_w = (const float*)d_in[12];
    hp.fc1_b = (const float*)d_in[13];
    hp.fin_w = (const float*)d_in[14];
    hp.fin_b = (const float*)d_in[15];
    hp.wp = wp;
    hp.adjp = adjp;
    hp.gpairs = gpairs;
    hp.out = (float*)d_out;

    hipLaunchKernelGGL(pack_k, dim3(258), dim3(64), 0, stream,
                       hp.emb_w, hp.gc1_w, hp.gc2_w, hp.gc3_w, hp.adj,
                       (_Float16*)wp, (_Float16*)adjp);
    hipLaunchKernelGGL(graph_k, dim3(64), dim3(1024), 0, stream, hp);
}

// Round 14
// 172.172 us; speedup vs baseline: 1.2999x; 1.2999x over previous
//
#include <hip/hip_runtime.h>
#include <math.h>

// ---------------------------------------------------------------------------
// B=64 graphs, NN=133 nodes. R-selfpack (retry; round-11 submission died to
// a container flake — round-13 proved identical round-8 bytes run fine, so
// the failures were environmental). graph_k compute stages byte-identical
// to twice-validated round-8 (graph_k 78-80us, absmax 0.0; all-MFMA dense
// path, LDS-resident activations, orientation-matched layouts). Round-8's
// bottleneck was pack_k's adj section (64 blocks x 45 serial tiles, 79us):
//  - adjP[b] is consumed ONLY by graph block b => each block packs its own
//    adj in its prologue (45 tiles / 16 waves, 8 contiguous loads/lane,
//    hidden behind zero-init+prep; visible after first __syncthreads since
//    same-CU writes drain at the barrier).
//  - pack_k keeps only the 194 weight blocks (chain depth 8, ~3-5us).
// ---------------------------------------------------------------------------

#define NN 133
#define NPAIR 64
#define NW 16

#define A0 0
#define B0 37440
#define SH_HALFS 80448

typedef float v4f __attribute__((ext_vector_type(4)));
typedef _Float16 f16x8 __attribute__((ext_vector_type(8)));
typedef _Float16 f16x4 __attribute__((ext_vector_type(4)));
typedef _Float16 f16x2 __attribute__((ext_vector_type(2)));
typedef float f32x4 __attribute__((ext_vector_type(4)));

// packed-W segment offsets (halfs); tiles of 512 halfs = [64 lanes][8]
#define WP_EMB 0               // 10 mt * 3 ks
#define WP_GC1 15360           // 16 ct * 5 ks
#define WP_GC2 56320           // 8 ct * 8 ks
#define WP_GC3 89088           // 5 ct * 4 ks

struct Params {
    const float *x, *adj, *emb_w, *emb_b, *gc1_w, *gc1_b, *gc2_w, *gc2_b,
                *gc3_w, *gc3_b, *gc4_w, *gc4_b, *fc1_w, *fc1_b, *fin_w, *fin_b;
    const _Float16 *wp;
    _Float16 *adjp;            // [64][45 tiles][64 lanes][8] (self-packed)
    float2 *gpairs;
    float *out;
};

// -------- prelude: weight pack only (194 blocks x 64 threads) ---------------
__global__ __launch_bounds__(64)
void pack_k(const float* __restrict__ emb_w, const float* __restrict__ gc1_w,
            const float* __restrict__ gc2_w, const float* __restrict__ gc3_w,
            _Float16* __restrict__ wp)
{
    const int t = blockIdx.x, lane = threadIdx.x;
    const float* W; int K, N, NKS, off, u;
    if (t < 30)       { W = emb_w; K = 75;  N = 150; NKS = 3; off = WP_EMB; u = t; }
    else if (t < 110) { W = gc1_w; K = 150; N = 256; NKS = 5; off = WP_GC1; u = t - 30; }
    else if (t < 174) { W = gc2_w; K = 256; N = 128; NKS = 8; off = WP_GC2; u = t - 110; }
    else              { W = gc3_w; K = 128; N = 75;  NKS = 4; off = WP_GC3; u = t - 174; }
    const int ct = u / NKS, ks = u % NKS;
    const int col = ct * 16 + (lane & 15);
    const int kb  = ks * 32 + (lane >> 4) * 8;
    f16x8 v;
#pragma unroll
    for (int j = 0; j < 8; ++j) {
        const int kk = kb + j;
        float w = W[(size_t)min(kk, K - 1) * N + min(col, N - 1)];
        if (kk >= K || col >= N) w = 0.f;
        v[j] = (_Float16)w;
    }
    *reinterpret_cast<f16x8*>(wp + (size_t)off + (size_t)u * 512 + lane * 8) = v;
}

// -------- ballot prep: pairs -> GLOBAL, counts -> LDS -----------------------
__device__ __forceinline__ void prep_row_g(
    const float* __restrict__ ar, float2* __restrict__ pb,
    int2* __restrict__ cS, int r, int lane)
{
    const unsigned long long lt = (1ull << lane) - 1ull;
    int base0 = 0, base1 = 0;
#pragma unroll
    for (int s = 0; s < 3; ++s) {
        const int j = lane + 64 * s;
        const float a = (j < NN) ? ar[j] : 0.f;
        const bool f = a > 1e-5f;
        const bool g = (a > 0.f) && !f;
        const unsigned long long mf = __ballot(f);
        const unsigned long long mg = __ballot(g);
        if (f) pb[base0 + __popcll(mf & lt)] =
                   make_float2(a, __int_as_float(j));
        if (g) pb[(NPAIR - 1) - (base1 + __popcll(mg & lt))] =
                   make_float2(a, __int_as_float(j));
        base0 += __popcll(mf);
        base1 += __popcll(mg);
    }
    if (lane == 0) cS[r] = make_int2(base0, base1);
}

// -------- swapped GEMM (emb): D=h0^T -> h0 row-major. A=wpack, B=x LDS ------
template<int MT, int NKS, int SSRC, int SDST, int N>
__device__ __forceinline__ void gemm_rm(
    const _Float16* __restrict__ wpA, const _Float16* __restrict__ src,
    const float* __restrict__ bias, _Float16* __restrict__ dst,
    int wave, int lane)
{
    const int lrow = lane & 15, lkb = lane >> 4;
    for (int t = wave; t < MT * 9; t += NW) {
        const int mt = t % MT, nt = t / MT;
        const _Float16* ap = wpA + (size_t)(mt * NKS) * 512 + lane * 8;
        const _Float16* bp = src + (nt * 16 + lrow) * SSRC + lkb * 8;
        f32x4 acc = {0.f, 0.f, 0.f, 0.f};
#pragma unroll
        for (int ks = 0; ks < NKS; ++ks) {
            f16x8 a = *reinterpret_cast<const f16x8*>(ap + ks * 512);
            f16x8 b = *reinterpret_cast<const f16x8*>(bp + ks * 32);
            acc = __builtin_amdgcn_mfma_f32_16x16x32_f16(a, b, acc, 0, 0, 0);
        }
        const int row = nt * 16 + lrow;
        const int c0  = mt * 16 + lkb * 4;
        f16x4 o;
#pragma unroll
        for (int i = 0; i < 4; ++i) {
            const int c = c0 + i;
            float v = 0.f;
            if (c < N) v = fmaxf(acc[i] + bias[c], 0.f);
            o[i] = (_Float16)v;
        }
        *reinterpret_cast<f16x4*>(dst + row * SDST + c0) = o;
    }
}

// -------- normal GEMM: t = p@W -> t col-major (b64). A=p LDS, B=wpack -------
template<int CT, int NKS, int SSRC>
__device__ __forceinline__ void gemm_cm(
    const _Float16* __restrict__ src, const _Float16* __restrict__ wpB,
    _Float16* __restrict__ t_cm, int wave, int lane)
{
    const int lrow = lane & 15, lkb = lane >> 4;
    for (int t = wave; t < CT * 9; t += NW) {
        const int ct = t % CT, rt = t / CT;
        const _Float16* ap = src + (rt * 16 + lrow) * SSRC + lkb * 8;
        const _Float16* bp = wpB + (size_t)(ct * NKS) * 512 + lane * 8;
        f32x4 acc = {0.f, 0.f, 0.f, 0.f};
#pragma unroll
        for (int ks = 0; ks < NKS; ++ks) {
            f16x8 a = *reinterpret_cast<const f16x8*>(ap + ks * 32);
            f16x8 b = *reinterpret_cast<const f16x8*>(bp + ks * 512);
            acc = __builtin_amdgcn_mfma_f32_16x16x32_f16(a, b, acc, 0, 0, 0);
        }
        const int col = ct * 16 + lrow;
        const int r0  = rt * 16 + lkb * 4;
        f16x4 o;
#pragma unroll
        for (int i = 0; i < 4; ++i) o[i] = (_Float16)acc[i];
        *reinterpret_cast<f16x4*>(t_cm + col * 168 + r0) = o;
    }
}

// -------- spmm: y^T = t^T (LDS) * adj^T (adjP) -> y row-major (b64) ---------
template<int MT, int SDST, int N>
__device__ __forceinline__ void spmm_mfma(
    const _Float16* __restrict__ t_cm, const _Float16* __restrict__ adjB,
    const float* __restrict__ bias, _Float16* __restrict__ y,
    int wave, int lane)
{
    const int lrow = lane & 15, lkb = lane >> 4;
    for (int t = wave; t < MT * 9; t += NW) {
        const int mt = t % MT, nt = t / MT;
        const _Float16* ap = t_cm + (mt * 16 + lrow) * 168 + lkb * 8;
        const _Float16* bp = adjB + (size_t)(nt * 5) * 512 + lane * 8;
        f32x4 acc = {0.f, 0.f, 0.f, 0.f};
#pragma unroll
        for (int ks = 0; ks < 5; ++ks) {
            f16x8 a = *reinterpret_cast<const f16x8*>(ap + ks * 32);
            f16x8 b = *reinterpret_cast<const f16x8*>(bp + ks * 512);
            acc = __builtin_amdgcn_mfma_f32_16x16x32_f16(a, b, acc, 0, 0, 0);
        }
        const int row = nt * 16 + lrow;
        const int c0  = mt * 16 + lkb * 4;
        f16x4 o;
#pragma unroll
        for (int i = 0; i < 4; ++i) {
            const int c = c0 + i;
            float v = 0.f;
            if (c < N) v = fmaxf(acc[i] + bias[c], 0.f);
            o[i] = (_Float16)v;
        }
        *reinterpret_cast<f16x4*>(y + row * SDST + c0) = o;
    }
}

// -------- pool, 4 cols/lane (N=256): y1(260) -> p1(264) ---------------------
__device__ __forceinline__ void pool4(
    const _Float16* __restrict__ yb,
    const float2* __restrict__ pb, int cx,
    _Float16* __restrict__ prow, int lane)
{
    const int c0 = 4 * lane;
    const float4* pq = reinterpret_cast<const float4*>(pb);
    float m0[4] = {}, m1[4] = {}, m2[4] = {}, m3[4] = {};
    int q = 0;
    for (; q + 4 <= cx; q += 4) {
        float4 p0 = pq[q >> 1], p1 = pq[(q >> 1) + 1];
        f16x4 r0 = *(const f16x4*)(yb + __float_as_int(p0.y) * 260 + c0);
        f16x4 r1 = *(const f16x4*)(yb + __float_as_int(p0.w) * 260 + c0);
        f16x4 r2 = *(const f16x4*)(yb + __float_as_int(p1.y) * 260 + c0);
        f16x4 r3 = *(const f16x4*)(yb + __float_as_int(p1.w) * 260 + c0);
#pragma unroll
        for (int u = 0; u < 4; ++u) {
            m0[u] = fmaxf(m0[u], (float)r0[u]);
            m1[u] = fmaxf(m1[u], (float)r1[u]);
            m2[u] = fmaxf(m2[u], (float)r2[u]);
            m3[u] = fmaxf(m3[u], (float)r3[u]);
        }
    }
    for (; q < cx; ++q) {
        f16x4 r = *(const f16x4*)(yb + __float_as_int(pb[q].y) * 260 + c0);
#pragma unroll
        for (int u = 0; u < 4; ++u) m0[u] = fmaxf(m0[u], (float)r[u]);
    }
    f16x4 o;
#pragma unroll
    for (int u = 0; u < 4; ++u)
        o[u] = (_Float16)fmaxf(fmaxf(m0[u], m1[u]), fmaxf(m2[u], m3[u]));
    *(f16x4*)(prow + c0) = o;
}

// -------- pool, 2 cols/lane (N=128): y2(136) -> p2(136) ---------------------
__device__ __forceinline__ void pool2(
    const _Float16* __restrict__ yb,
    const float2* __restrict__ pb, int cx,
    _Float16* __restrict__ prow, int lane)
{
    const int c0 = 2 * lane;
    if (c0 >= 128) return;
    const float4* pq = reinterpret_cast<const float4*>(pb);
    float m0[2] = {}, m1[2] = {}, m2[2] = {}, m3[2] = {};
    int q = 0;
    for (; q + 4 <= cx; q += 4) {
        float4 p0 = pq[q >> 1], p1 = pq[(q >> 1) + 1];
        f16x2 r0 = *(const f16x2*)(yb + __float_as_int(p0.y) * 136 + c0);
        f16x2 r1 = *(const f16x2*)(yb + __float_as_int(p0.w) * 136 + c0);
        f16x2 r2 = *(const f16x2*)(yb + __float_as_int(p1.y) * 136 + c0);
        f16x2 r3 = *(const f16x2*)(yb + __float_as_int(p1.w) * 136 + c0);
#pragma unroll
        for (int u = 0; u < 2; ++u) {
            m0[u] = fmaxf(m0[u], (float)r0[u]);
            m1[u] = fmaxf(m1[u], (float)r1[u]);
            m2[u] = fmaxf(m2[u], (float)r2[u]);
            m3[u] = fmaxf(m3[u], (float)r3[u]);
        }
    }
    for (; q < cx; ++q) {
        f16x2 r = *(const f16x2*)(yb + __float_as_int(pb[q].y) * 136 + c0);
#pragma unroll
        for (int u = 0; u < 2; ++u) m0[u] = fmaxf(m0[u], (float)r[u]);
    }
    f16x2 o;
#pragma unroll
    for (int u = 0; u < 2; ++u)
        o[u] = (_Float16)fmaxf(fmaxf(m0[u], m1[u]), fmaxf(m2[u], m3[u]));
    *(f16x2*)(prow + c0) = o;
}

// -------- t4: 2 cols/lane b32 reads from y3(80) -----------------------------
__device__ __forceinline__ void t4_row(
    const _Float16* __restrict__ yb,
    const float2* __restrict__ pb, int cx,
    const float* __restrict__ gc4_w,
    float* __restrict__ t4S, int r, int lane)
{
    const int c0 = 2 * lane;
    const int sc = min(c0, 78);
    const float gw0 = (c0 < 75) ? gc4_w[c0] : 0.f;
    const float gw1 = (c0 + 1 < 75) ? gc4_w[c0 + 1] : 0.f;
    const float4* pq = reinterpret_cast<const float4*>(pb);
    float m0a = 0.f, m1a = 0.f, m0b = 0.f, m1b = 0.f;
    float m0c = 0.f, m1c = 0.f, m0d = 0.f, m1d = 0.f;
    int q = 0;
    for (; q + 4 <= cx; q += 4) {
        float4 pA = pq[q >> 1], pB = pq[(q >> 1) + 1];
        f16x2 r0 = *(const f16x2*)(yb + __float_as_int(pA.y) * 80 + sc);
        f16x2 r1 = *(const f16x2*)(yb + __float_as_int(pA.w) * 80 + sc);
        f16x2 r2 = *(const f16x2*)(yb + __float_as_int(pB.y) * 80 + sc);
        f16x2 r3 = *(const f16x2*)(yb + __float_as_int(pB.w) * 80 + sc);
        m0a = fmaxf(m0a, (float)r0[0]); m1a = fmaxf(m1a, (float)r0[1]);
        m0b = fmaxf(m0b, (float)r1[0]); m1b = fmaxf(m1b, (float)r1[1]);
        m0c = fmaxf(m0c, (float)r2[0]); m1c = fmaxf(m1c, (float)r2[1]);
        m0d = fmaxf(m0d, (float)r3[0]); m1d = fmaxf(m1d, (float)r3[1]);
    }
    for (; q < cx; ++q) {
        f16x2 r = *(const f16x2*)(yb + __float_as_int(pb[q].y) * 80 + sc);
        m0a = fmaxf(m0a, (float)r[0]); m1a = fmaxf(m1a, (float)r[1]);
    }
    float m0 = fmaxf(fmaxf(m0a, m0b), fmaxf(m0c, m0d));
    float m1 = fmaxf(fmaxf(m1a, m1b), fmaxf(m1c, m1d));
    float v = m0 * gw0 + m1 * gw1;
#pragma unroll
    for (int off = 32; off; off >>= 1) v += __shfl_xor(v, off, 64);
    if (lane == 0) t4S[r] = v;
}

// --------------------------- one block = one graph --------------------------
__global__ __launch_bounds__(1024, 1)
void graph_k(Params P)
{
    __shared__ __align__(16) _Float16 SH[SH_HALFS];      // 160,896 B
    __shared__ int2  cS[NN];
    __shared__ float t4S[NN];
    __shared__ float y4S[NN];
    __shared__ float rS[3];

    const int b    = blockIdx.x;
    const int tid  = threadIdx.x;
    const int wave = tid >> 6, lane = tid & 63;

    float2* gp = P.gpairs + (size_t)b * NN * NPAIR;
    const _Float16* adjB = P.adjp + (size_t)b * 45 * 512;

    // S0: zero scratch + ballot prep + SELF-PACK this graph's adj fragments.
    // adjP[b] is only read by this block, after __syncthreads (same-CU writes
    // drain at the barrier) => no cross-block dependency.
    {
        v4f* z = reinterpret_cast<v4f*>(&SH[0]);
        for (int i = tid; i < SH_HALFS / 8; i += 1024)
            z[i] = v4f{0.f, 0.f, 0.f, 0.f};
    }
    for (int r = wave; r < NN; r += NW)
        prep_row_g(P.adj + ((size_t)b * NN + r) * NN, gp + (size_t)r * NPAIR,
                   cS, r, lane);
    {
        const float* ag = P.adj + (size_t)b * NN * NN;
        _Float16* ap = P.adjp + (size_t)b * 45 * 512;
        for (int u = wave; u < 45; u += NW) {
            const int n  = (u / 5) * 16 + (lane & 15);
            const int kb = (u % 5) * 32 + (lane >> 4) * 8;
            f16x8 v;
#pragma unroll
            for (int j = 0; j < 8; ++j) {
                const int kk = kb + j;
                float w = (n < NN && kk < NN) ? ag[(size_t)n * NN + kk] : 0.f;
                v[j] = (_Float16)w;
            }
            *reinterpret_cast<f16x8*>(ap + (size_t)u * 512 + lane * 8) = v;
        }
    }
    __syncthreads();
    // S0a: x -> B0 row-major f16 (stride 104)
    for (int i = tid; i < NN * 75; i += 1024) {
        int r = i / 75, c = i - r * 75;
        SH[B0 + r * 104 + c] = (_Float16)P.x[(size_t)b * NN * 75 + i];
    }
    __syncthreads();
    // S1: emb (swapped): h0 = relu(x@emb_w+b) -> A0 row-major (stride 168)
    gemm_rm<10, 3, 104, 168, 150>(P.wp + WP_EMB, SH + B0, P.emb_b,
                                  SH + A0, wave, lane);
    __syncthreads();
    // S2: gemm1: t1 = h0 @ gc1_w -> B0 col-major (256 cols x 168)
    gemm_cm<16, 5, 168>(SH + A0, P.wp + WP_GC1, SH + B0, wave, lane);
    __syncthreads();
    // S3: spmm1: y1 = relu(adj@t1+b1) -> A0 row-major (stride 260)
    spmm_mfma<16, 260, 256>(SH + B0, adjB, P.gc1_b, SH + A0, wave, lane);
    __syncthreads();
    // S4: pool1: p1 -> B0 row-major (stride 264)
    for (int r = wave; r < NN; r += NW)
        pool4(SH + A0, gp + (size_t)r * NPAIR, cS[r].x,
              SH + B0 + r * 264, lane);
    __syncthreads();
    // S5: gemm2: t2 = p1 @ gc2_w -> A0 col-major (128 cols x 168)
    gemm_cm<8, 8, 264>(SH + B0, P.wp + WP_GC2, SH + A0, wave, lane);
    __syncthreads();
    // S6: spmm2: y2 -> B0 row-major (stride 136)
    spmm_mfma<8, 136, 128>(SH + A0, adjB, P.gc2_b, SH + B0, wave, lane);
    __syncthreads();
    // S7: pool2: p2 -> A0 row-major (stride 136)
    for (int r = wave; r < NN; r += NW)
        pool2(SH + B0, gp + (size_t)r * NPAIR, cS[r].x,
              SH + A0 + r * 136, lane);
    __syncthreads();
    // S8: gemm3: t3 = p2 @ gc3_w -> B0 col-major (80 cols x 168)
    gemm_cm<5, 4, 136>(SH + A0, P.wp + WP_GC3, SH + B0, wave, lane);
    __syncthreads();
    // S9: spmm3: y3 -> A0 row-major (stride 80, N=75)
    spmm_mfma<5, 80, 75>(SH + B0, adjB, P.gc3_b, SH + A0, wave, lane);
    __syncthreads();
    // S10: t4S[r] = pool3(y3)[r] . gc4_w
    for (int r = wave; r < NN; r += NW)
        t4_row(SH + A0, gp + (size_t)r * NPAIR, cS[r].x, P.gc4_w,
               t4S, r, lane);
    __syncthreads();
    // S11: tail — y4 = relu(A@t4+b4); fc1; fin; sigmoid
    if (tid < NN) {
        const float2* pb = gp + (size_t)tid * NPAIR;
        int2 c = cS[tid];
        float s = P.gc4_b[0];
        for (int q = 0; q < c.x; ++q) {
            float2 f = pb[q];
            s = fmaf(f.x, t4S[__float_as_int(f.y)], s);
        }
        for (int q = 0; q < c.y; ++q) {
            float2 f = pb[(NPAIR - 1) - q];
            s = fmaf(f.x, t4S[__float_as_int(f.y)], s);
        }
        y4S[tid] = fmaxf(s, 0.f);
    }
    __syncthreads();
    if (tid < 3) {
        float s = P.fc1_b[tid];
        for (int j = 0; j < 132; ++j)
            s = fmaf(y4S[1 + j], P.fc1_w[j * 3 + tid], s);
        rS[tid] = s;
    }
    __syncthreads();
    if (tid == 0) {
        float z = P.fin_b[0] + y4S[0] * P.fin_w[0] + rS[0] * P.fin_w[1]
                + rS[1] * P.fin_w[2] + rS[2] * P.fin_w[3];
        P.out[b] = 1.f / (1.f + expf(-z));
    }
}

extern "C" void kernel_launch(void* const* d_in, const int* in_sizes, int n_in,
                              void* d_out, int out_size, void* d_ws, size_t ws_size,
                              hipStream_t stream)
{
    // ws: wpack 199KB (->256KB) | adjP 2.95MB (->3MB) | gpairs 4.36MB
    _Float16* wp     = (_Float16*)d_ws;
    _Float16* adjp   = (_Float16*)((char*)d_ws + (256 << 10));
    float2*   gpairs = (float2*)((char*)d_ws + (256 << 10) + (3 << 20));

    Params hp;
    hp.x     = (const float*)d_in[0];
    hp.adj   = (const float*)d_in[1];
    hp.emb_w = (const float*)d_in[2];
    hp.emb_b = (const float*)d_in[3];
    hp.gc1_w = (const float*)d_in[4];
    hp.gc1_b = (const float*)d_in[5];
    hp.gc2_w = (const float*)d_in[6];
    hp.gc2_b = (const float*)d_in[7];
    hp.gc3_w = (const float*)d_in[8];
    hp.gc3_b = (const float*)d_in[9];
    hp.gc4_w = (const float*)d_in[10];
    hp.gc4_b = (const float*)d_in[11];
    hp.fc1_w = (const float*)d_in[12];
    hp.fc1_b = (const float*)d_in[13];
    hp.fin_w = (const float*)d_in[14];
    hp.fin_b = (const float*)d_in[15];
    hp.wp = wp;
    hp.adjp = adjp;
    hp.gpairs = gpairs;
    hp.out = (float*)d_out;

    hipLaunchKernelGGL(pack_k, dim3(194), dim3(64), 0, stream,
                       hp.emb_w, hp.gc1_w, hp.gc2_w, hp.gc3_w, wp);
    hipLaunchKernelGGL(graph_k, dim3(64), dim3(1024), 0, stream, hp);
}